// Round 3
// baseline (285.922 us; speedup 1.0000x reference)
//
#include <hip/hip_runtime.h>
#include <hip/hip_bf16.h>

#define BATCH 8
#define CH    64
#define HH    112
#define WW    112
#define HW    (HH * WW)          // 12544
#define NP    (BATCH * HW)       // 100352 pixels
#define TAPS  25
#define MIDC  256
#define PIX   64                 // pixels per block
#define CPW   16                 // channels per wave (4 waves * 16 = 64)
#define STRIPS (HW / PIX)        // 196 strips per image

// ---------------------------------------------------------------------------
// Kernel A: fold conv2 (1x1, 256->25) into conv1 weights.
//   weff[ctap][o] = sum_mid w2[o][mid] * w1[mid][ctap]     (ctap = c*25+tap)
// Thread t = o*1600 + ctap: o is wave-uniform (1600 % 64 == 0) -> w2 row via
// scalar loads; w1 reads are lane-coalesced (consecutive ctap).
// ---------------------------------------------------------------------------
__global__ __launch_bounds__(256) void weff_kernel(
    const float* __restrict__ w1, const float* __restrict__ b1,
    const float* __restrict__ w2, const float* __restrict__ b2,
    float* __restrict__ weff, float* __restrict__ beff) {
  int t = blockIdx.x * 256 + threadIdx.x;
  if (t < TAPS * CH * TAPS) {
    int o    = t / (CH * TAPS);          // wave-uniform
    int ctap = t % (CH * TAPS);
    const float* w2o = w2 + o * MIDC;
    float acc = 0.f;
    #pragma unroll 8
    for (int mid = 0; mid < MIDC; ++mid)
      acc = fmaf(w1[(size_t)mid * (CH * TAPS) + ctap], w2o[mid], acc);
    weff[ctap * TAPS + o] = acc;
  }
  if (blockIdx.x == 0 && threadIdx.x < TAPS) {
    int o = threadIdx.x;
    float b = b2[o];
    for (int mid = 0; mid < MIDC; ++mid) b += w2[o * MIDC + mid] * b1[mid];
    beff[o] = b;
  }
}

// ---------------------------------------------------------------------------
// Kernel B: fused logits -> cross-wave reduce -> softmax -> weighted gather.
// Block = 256 threads = 4 waves; 64 pixels/block; wave w owns 16 channels.
// XCD swizzle: image = blockIdx % 8, strip = blockIdx / 8. Round-robin
// dispatch puts each image on one XCD -> 3.2 MB working set fits 4 MB L2.
// ---------------------------------------------------------------------------
__global__ __launch_bounds__(256) void picanet_main(
    const float* __restrict__ x, const float* __restrict__ weff,
    const float* __restrict__ beff, float* __restrict__ out) {
  __shared__ float red[4 * PIX * TAPS];       // 25.6 KB -> 6 blocks/CU by LDS

  const int lane = threadIdx.x & 63;
  const int wave = threadIdx.x >> 6;
  const int c0 = __builtin_amdgcn_readfirstlane(wave * CPW);

  const int b     = blockIdx.x & 7;           // XCD-aligned image id
  const int strip = blockIdx.x >> 3;          // 0..195
  const int hw = strip * PIX + lane;
  const int h  = hw / WW;
  const int w  = hw % WW;

  const float* xb = x + (size_t)b * CH * HW + (size_t)c0 * HW;
  const float* wc = weff + (size_t)c0 * TAPS * TAPS;

  // ---- Phase 1: partial logits over this wave's 16 channels ----
  float s[TAPS];
  #pragma unroll
  for (int o = 0; o < TAPS; ++o) s[o] = 0.f;

  #pragma unroll 1
  for (int tap = 0; tap < TAPS; ++tap) {
    int i = tap / 5, j = tap % 5;
    int yy = h + 2 * i - 4;
    int xx = w + 2 * j - 4;
    bool ok = (yy >= 0) & (yy < HH) & (xx >= 0) & (xx < WW);
    int   offt = ok ? yy * WW + xx : 0;
    float mk   = ok ? 1.f : 0.f;
    const float* wt = wc + tap * TAPS;
    #pragma unroll
    for (int c = 0; c < CPW; ++c) {
      float xv = xb[(size_t)c * HW + offt] * mk;
      const float* wp = wt + c * (TAPS * TAPS);   // uniform -> scalar loads
      #pragma unroll
      for (int o = 0; o < TAPS; ++o) s[o] = fmaf(xv, wp[o], s[o]);
    }
  }

  #pragma unroll
  for (int o = 0; o < TAPS; ++o) red[(wave * PIX + lane) * TAPS + o] = s[o];
  __syncthreads();

  // ---- Softmax (wave 0 handles all 64 pixels of the block) ----
  if (wave == 0) {
    float t[TAPS];
    #pragma unroll
    for (int o = 0; o < TAPS; ++o)
      t[o] = red[lane * TAPS + o] + red[(PIX + lane) * TAPS + o] +
             red[(2 * PIX + lane) * TAPS + o] + red[(3 * PIX + lane) * TAPS + o] +
             beff[o];
    float m = t[0];
    #pragma unroll
    for (int o = 1; o < TAPS; ++o) m = fmaxf(m, t[o]);
    float sum = 0.f;
    #pragma unroll
    for (int o = 0; o < TAPS; ++o) { t[o] = __expf(t[o] - m); sum += t[o]; }
    float inv = 1.f / sum;
    #pragma unroll
    for (int o = 0; o < TAPS; ++o) {
      int i = o / 5, j = o % 5;
      int yy = h + 2 * i - 4;
      int xx = w + 2 * j - 4;
      bool ok = (yy >= 0) & (yy < HH) & (xx >= 0) & (xx < WW);
      red[lane * TAPS + o] = ok ? t[o] * inv : 0.f;
    }
  }
  __syncthreads();

  // ---- Phase 2: out[b,c,h,w] = sum_tap sfin[tap] * x[b,c,tap(h,w)] ----
  float acc[CPW];
  #pragma unroll
  for (int c = 0; c < CPW; ++c) acc[c] = 0.f;

  #pragma unroll 1
  for (int tap = 0; tap < TAPS; ++tap) {
    int i = tap / 5, j = tap % 5;
    int yy = h + 2 * i - 4;
    int xx = w + 2 * j - 4;
    bool ok = (yy >= 0) & (yy < HH) & (xx >= 0) & (xx < WW);
    int offt = ok ? yy * WW + xx : 0;      // invalid taps have sfin == 0
    float sv = red[lane * TAPS + tap];
    #pragma unroll
    for (int c = 0; c < CPW; ++c)
      acc[c] = fmaf(sv, xb[(size_t)c * HW + offt], acc[c]);
  }

  float* ob = out + (size_t)b * CH * HW + (size_t)c0 * HW + hw;
  #pragma unroll
  for (int c = 0; c < CPW; ++c) ob[c * HW] = acc[c];
}

extern "C" void kernel_launch(void* const* d_in, const int* in_sizes, int n_in,
                              void* d_out, int out_size, void* d_ws, size_t ws_size,
                              hipStream_t stream) {
  const float* x  = (const float*)d_in[0];
  const float* w1 = (const float*)d_in[1];
  const float* b1 = (const float*)d_in[2];
  const float* w2 = (const float*)d_in[3];
  const float* b2 = (const float*)d_in[4];
  float* out  = (float*)d_out;
  float* weff = (float*)d_ws;                       // 40000 floats
  float* beff = weff + CH * TAPS * TAPS;            // 25 floats

  int nA = TAPS * CH * TAPS;                        // 40000
  weff_kernel<<<(nA + 255) / 256, 256, 0, stream>>>(w1, b1, w2, b2, weff, beff);
  picanet_main<<<BATCH * STRIPS, 256, 0, stream>>>(x, weff, beff, out);
}